// Round 1
// baseline (741.000 us; speedup 1.0000x reference)
//
#include <hip/hip_runtime.h>

#define L_ 2
#define T_ 512
#define B_ 128
#define F_ 4
#define H_ 256
#define QSIGN_MASK 0x5390

typedef __attribute__((ext_vector_type(8))) short short8;
typedef __attribute__((ext_vector_type(4))) float f32x4;

// Mailbox: layer-0 normalized output, bf16x4 packed per (t,b); norm-1 => nonzero.
__device__ unsigned long long g_inter_q[T_][B_];

__global__ void zero_inter() {
  ((unsigned long long*)g_inter_q)[blockIdx.x * 256 + threadIdx.x] = 0ull;
}

__device__ __forceinline__ unsigned f2bf(float f) {
  unsigned u = __float_as_uint(f);
  return (u + 0x7fff + ((u >> 16) & 1)) >> 16;
}
__device__ __forceinline__ float fast_sigmoid(float x) { return 1.f / (1.f + __expf(-x)); }
__device__ __forceinline__ float fast_tanh(float x) {
  float a = fabsf(x), e = __expf(2.f * a);
  return copysignf(1.f - 2.f / (e + 1.f), x);
}
__device__ __forceinline__ unsigned long long pack4bf(float a, float b, float c, float d) {
  return (unsigned long long)f2bf(a)
       | ((unsigned long long)f2bf(b) << 16)
       | ((unsigned long long)f2bf(c) << 32)
       | ((unsigned long long)f2bf(d) << 48);
}

union FragU { short8 v; uint4 u; unsigned w[4]; };

// Raw workgroup barrier: drains LDS ops only. Deliberately does NOT drain vmcnt,
// so helper-wave global loads (x / mailbox) and mailbox stores stay in flight
// across the barrier (__syncthreads would force vmcnt(0) = full store-ack +
// load-completion drain every step). sched_barrier(0) on both sides pins code
// motion (rule 18/21 precaution).
#define BAR() do { \
  __builtin_amdgcn_sched_barrier(0); \
  asm volatile("s_waitcnt lgkmcnt(0)" ::: "memory"); \
  __builtin_amdgcn_s_barrier(); \
  __builtin_amdgcn_sched_barrier(0); \
} while (0)

// Grid = 64 WGs x 320 threads (5 waves). blockIdx<32: layer-0 producer; else layer-1.
// Compute waves 0-3: wave w owns cols u in [16w,16w+16). MFMA M rows = b*4+q
// (b=quad, q=reg in C/D), N = u16, LSTM update fully in-lane, one barrier/step.
// Gate accumulators split into even/odd-ks chains (5+4 deep) to halve dependent
// MFMA latency.
// Helper wave 4: projection via MFMA (P^T[f][b] = fw^T . h), split 4+4 chains;
// publishes mailbox EVERY step (stores are fire-and-forget under raw barrier).
// x/mailbox staging is truly pipelined: global load for entry s+3 is ISSUED at
// step s, its value is packed/stored to sh_x at step s+1 -> one full barrier
// interval of latency hiding; the load never sits on the barrier critical path.
__launch_bounds__(320, 1)
__global__ void qlstm_fused(const float* __restrict__ x_in,
                            const float* __restrict__ uhr, const float* __restrict__ uhi,
                            const float* __restrict__ uhj, const float* __restrict__ uhk,
                            const float* __restrict__ wxr, const float* __restrict__ wxi,
                            const float* __restrict__ wxj, const float* __restrict__ wxk,
                            const float* __restrict__ wxb_all,
                            const float* __restrict__ fcw_all, const float* __restrict__ fcb_all,
                            float* __restrict__ out_final)
{
  __shared__ __align__(16) unsigned short sh_h[2][4][272];  // double-buffered h (bf16)
  __shared__ unsigned long long sh_x[4][4];                 // ring-4 x, bf16x4 packed

  const int t     = threadIdx.x;
  const int role  = blockIdx.x >> 5;
  const int bg    = blockIdx.x & 31;
  const int bg0   = bg * 4;
  const int layer = role;
  const int wv    = t >> 6;
  const int lane  = t & 63;
  const int quad  = lane >> 4;
  const int sub   = lane & 15;

  const float* wb = wxb_all + layer * 4 * H_;
  const float* fw = fcw_all + layer * H_ * F_;
  const float* fb = fcb_all + layer * F_;

  for (int i = t; i < 2176; i += 320) ((unsigned short*)sh_h)[i] = 0;

  if (wv < 4) {
    // ================= COMPUTE WAVES =================
    const int u  = wv * 16 + sub;   // B n-col / D col
    const int ba = sub >> 2;        // A-side row -> batch
    const int qa = sub & 3;         // A-side row -> q

    // persistent B fragments [g][ks]: raw component blocks (d=ks>>1, p-half=ks&1)
    FragU Bf[32];
    FragU Bx[4];
    float bv[4][4];
    {
      const float* Cc[4] = {uhr, uhi, uhj, uhk};
      const float* Xc[4] = {wxr, wxi, wxj, wxk};
      #pragma unroll
      for (int g = 0; g < 4; ++g) {
        #pragma unroll
        for (int ks = 0; ks < 8; ++ks) {
          const int d  = ks >> 1;
          const int pp = (ks & 1) * 32 + quad * 8;
          const float* src = Cc[d] + (size_t)((layer * 4 + g) * 64 + pp) * 64 + u;
          FragU f;
          #pragma unroll
          for (int j = 0; j < 8; ++j) f.v[j] = (short)f2bf(src[j * 64]);
          Bf[g * 8 + ks] = f;
        }
        FragU fx; fx.w[0] = 0; fx.w[1] = 0; fx.w[2] = 0; fx.w[3] = 0;
        if (quad == 0) {
          unsigned e0 = f2bf(Xc[0][(layer * 4 + g) * 64 + u]);
          unsigned e1 = f2bf(Xc[1][(layer * 4 + g) * 64 + u]);
          unsigned e2 = f2bf(Xc[2][(layer * 4 + g) * 64 + u]);
          unsigned e3 = f2bf(Xc[3][(layer * 4 + g) * 64 + u]);
          fx.w[0] = e0 | (e1 << 16);
          fx.w[1] = e2 | (e3 << 16);
        }
        Bx[g] = fx;
        #pragma unroll
        for (int r = 0; r < 4; ++r) bv[g][r] = wb[g * 256 + r * 64 + u];
      }
    }
    // sign masks (a = qa^d) and A-read byte offsets
    unsigned smask[4], smx[4];
    int xsh[4], aoff[8];
    #pragma unroll
    for (int d = 0; d < 4; ++d) {
      const int a = qa ^ d;
      const bool neg = (QSIGN_MASK >> (a * 4 + qa)) & 1;
      smask[d] = neg ? 0x80008000u : 0u;
      smx[d]   = neg ? 0x8000u : 0u;
      xsh[d]   = 16 * a;
    }
    #pragma unroll
    for (int ks = 0; ks < 8; ++ks)
      aoff[ks] = ba * 544 + (((qa ^ (ks >> 1)) * 64 + (ks & 1) * 32 + quad * 8) << 1);
    float cs[4] = {0.f, 0.f, 0.f, 0.f};
    BAR();

    const char* hbB = (const char*)sh_h;
    for (int s = 0; s <= T_; ++s) {
      if (s < T_) {
        const char* hp = hbB + ((s + 1) & 1) * 2176;   // h[s-1]
        // x A-frag: k=d (0..3), value = sign(a,q)*x[b][a], a=q^d
        unsigned long long xq = sh_x[s & 3][ba];
        FragU Ax; Ax.w[0] = 0; Ax.w[1] = 0; Ax.w[2] = 0; Ax.w[3] = 0;
        if (quad == 0) {
          unsigned e0 = ((unsigned)(xq >> xsh[0]) & 0xffffu) ^ smx[0];
          unsigned e1 = ((unsigned)(xq >> xsh[1]) & 0xffffu) ^ smx[1];
          unsigned e2 = ((unsigned)(xq >> xsh[2]) & 0xffffu) ^ smx[2];
          unsigned e3 = ((unsigned)(xq >> xsh[3]) & 0xffffu) ^ smx[3];
          Ax.w[0] = e0 | (e1 << 16);
          Ax.w[1] = e2 | (e3 << 16);
        }
        // even/odd-ks split accumulators: chains of 5 (bias+x+even ks) and 4 (odd ks)
        f32x4 a0 = {bv[0][0], bv[0][1], bv[0][2], bv[0][3]};
        f32x4 a1 = {bv[1][0], bv[1][1], bv[1][2], bv[1][3]};
        f32x4 a2 = {bv[2][0], bv[2][1], bv[2][2], bv[2][3]};
        f32x4 a3 = {bv[3][0], bv[3][1], bv[3][2], bv[3][3]};
        f32x4 b0 = {0.f, 0.f, 0.f, 0.f};
        f32x4 b1 = b0, b2 = b0, b3 = b0;
        a0 = __builtin_amdgcn_mfma_f32_16x16x32_bf16(Ax.v, Bx[0].v, a0, 0, 0, 0);
        a1 = __builtin_amdgcn_mfma_f32_16x16x32_bf16(Ax.v, Bx[1].v, a1, 0, 0, 0);
        a2 = __builtin_amdgcn_mfma_f32_16x16x32_bf16(Ax.v, Bx[2].v, a2, 0, 0, 0);
        a3 = __builtin_amdgcn_mfma_f32_16x16x32_bf16(Ax.v, Bx[3].v, a3, 0, 0, 0);
        #pragma unroll
        for (int ks = 0; ks < 8; ++ks) {
          FragU A;
          A.u = *(const uint4*)(hp + aoff[ks]);
          const unsigned m = smask[ks >> 1];
          A.w[0] ^= m; A.w[1] ^= m; A.w[2] ^= m; A.w[3] ^= m;
          if (ks & 1) {
            b0 = __builtin_amdgcn_mfma_f32_16x16x32_bf16(A.v, Bf[0 * 8 + ks].v, b0, 0, 0, 0);
            b1 = __builtin_amdgcn_mfma_f32_16x16x32_bf16(A.v, Bf[1 * 8 + ks].v, b1, 0, 0, 0);
            b2 = __builtin_amdgcn_mfma_f32_16x16x32_bf16(A.v, Bf[2 * 8 + ks].v, b2, 0, 0, 0);
            b3 = __builtin_amdgcn_mfma_f32_16x16x32_bf16(A.v, Bf[3 * 8 + ks].v, b3, 0, 0, 0);
          } else {
            a0 = __builtin_amdgcn_mfma_f32_16x16x32_bf16(A.v, Bf[0 * 8 + ks].v, a0, 0, 0, 0);
            a1 = __builtin_amdgcn_mfma_f32_16x16x32_bf16(A.v, Bf[1 * 8 + ks].v, a1, 0, 0, 0);
            a2 = __builtin_amdgcn_mfma_f32_16x16x32_bf16(A.v, Bf[2 * 8 + ks].v, a2, 0, 0, 0);
            a3 = __builtin_amdgcn_mfma_f32_16x16x32_bf16(A.v, Bf[3 * 8 + ks].v, a3, 0, 0, 0);
          }
        }
        // fully in-lane gates: b=quad, c = r*64+u for r=0..3
        char* hw = (char*)sh_h + (s & 1) * 2176 + quad * 544;
        #pragma unroll
        for (int r = 0; r < 4; ++r) {
          float fg = fast_sigmoid(a0[r] + b0[r]);
          float ig = fast_sigmoid(a1[r] + b1[r]);
          float og = fast_sigmoid(a2[r] + b2[r]);
          float cv = fast_tanh(a3[r] + b3[r]);
          cs[r] = ig * cv + fg * cs[r];
          float h = og * fast_tanh(cs[r]);
          *(unsigned short*)(hw + ((r * 64 + u) << 1)) = (unsigned short)f2bf(h);
        }
      }
      BAR();
    }
  } else {
    // ================= HELPER WAVE =================
    // fw^T A-frags: A[m=f][k] = fw[k][f], rows 4-15 zero
    FragU Af[8];
    #pragma unroll
    for (int ks = 0; ks < 8; ++ks) {
      FragU f;
      #pragma unroll
      for (int j = 0; j < 8; ++j) {
        const int k = ks * 32 + quad * 8 + j;
        f.v[j] = (sub < 4) ? (short)f2bf(fw[k * 4 + sub]) : (short)0;
      }
      Af[ks] = f;
    }
    const float fb0 = fb[0], fb1 = fb[1], fb2 = fb[2], fb3 = fb[3];
    const int bl = sub & 3;   // B-side col (batch), clamped for lanes >= 4

    // Pipeline state: entry s+3's raw value, load ISSUED at step s, consumed at s+1.
    float4 xnext = make_float4(0.f, 0.f, 0.f, 0.f);
    unsigned long long vnext = 0ull;

    // prologue: x slots 0,1,2 filled; entry 3's load issued.
    if (lane < 4) {
      if (role == 0) {
        #pragma unroll
        for (int s0 = 0; s0 < 3; ++s0) {
          float4 xv = *(const float4*)(x_in + (size_t)((bg0 + lane) * T_ + s0) * F_);
          sh_x[s0][lane] = pack4bf(xv.x, xv.y, xv.z, xv.w);
        }
        xnext = *(const float4*)(x_in + (size_t)((bg0 + lane) * T_ + 3) * F_);
      } else {
        #pragma unroll
        for (int s0 = 0; s0 < 3; ++s0) {
          unsigned long long v;
          while ((v = __hip_atomic_load(&g_inter_q[s0][bg0 + lane], __ATOMIC_RELAXED,
                                        __HIP_MEMORY_SCOPE_AGENT)) == 0ull)
            __builtin_amdgcn_s_sleep(1);
          sh_x[s0][lane] = v;
        }
        vnext = __hip_atomic_load(&g_inter_q[3][bg0 + lane], __ATOMIC_RELAXED,
                                  __HIP_MEMORY_SCOPE_AGENT);
      }
    }
    BAR();

    for (int s = 0; s <= T_; ++s) {
      const bool doproj = (s >= 1) && (role == 0 || s == T_);
      if (doproj) {
        const char* hp = (const char*)sh_h + ((s + 1) & 1) * 2176;  // h[s-1]
        f32x4 pa = {fb0, fb1, fb2, fb3};
        f32x4 pb = {0.f, 0.f, 0.f, 0.f};
        #pragma unroll
        for (int ks = 0; ks < 8; ++ks) {
          FragU Bh;
          Bh.u = *(const uint4*)(hp + bl * 544 + ((ks * 32 + quad * 8) << 1));
          if (ks & 1)
            pb = __builtin_amdgcn_mfma_f32_16x16x32_bf16(Af[ks].v, Bh.v, pb, 0, 0, 0);
          else
            pa = __builtin_amdgcn_mfma_f32_16x16x32_bf16(Af[ks].v, Bh.v, pa, 0, 0, 0);
        }
        if (lane < 4) {   // quad==0, sub<4: all 4 components in-reg, batch = lane
          float p0 = pa[0] + pb[0], p1 = pa[1] + pb[1];
          float p2 = pa[2] + pb[2], p3 = pa[3] + pb[3];
          float inv = 1.f / fmaxf(sqrtf(p0*p0 + p1*p1 + p2*p2 + p3*p3), 1e-12f);
          p0 *= inv; p1 *= inv; p2 *= inv; p3 *= inv;
          if (role == 0) {
            // publish every step; store is fire-and-forget (no vmcnt drain at BAR)
            __hip_atomic_store(&g_inter_q[s - 1][bg0 + lane], pack4bf(p0, p1, p2, p3),
                               __ATOMIC_RELAXED, __HIP_MEMORY_SCOPE_AGENT);
          } else {                     // consumer, s == T: final output
            *(float4*)(out_final + (bg0 + lane) * F_) = make_float4(p0, p1, p2, p3);
          }
        }
      }
      // Consume entry s+3 (load was issued at step s-1 -> latency already hidden),
      // then issue the load for entry s+4.
      if (lane < 4) {
        const int e = s + 3;
        if (e < T_) {
          if (role == 0) {
            sh_x[e & 3][lane] = pack4bf(xnext.x, xnext.y, xnext.z, xnext.w);
            if (e + 1 < T_)
              xnext = *(const float4*)(x_in + (size_t)((bg0 + lane) * T_ + e + 1) * F_);
          } else {
            unsigned long long v = vnext;
            while (v == 0ull) {        // slow path: only while lag < 4 steps
              __builtin_amdgcn_s_sleep(1);
              v = __hip_atomic_load(&g_inter_q[e][bg0 + lane], __ATOMIC_RELAXED,
                                    __HIP_MEMORY_SCOPE_AGENT);
            }
            sh_x[e & 3][lane] = v;
            if (e + 1 < T_)
              vnext = __hip_atomic_load(&g_inter_q[e + 1][bg0 + lane], __ATOMIC_RELAXED,
                                        __HIP_MEMORY_SCOPE_AGENT);
          }
        }
      }
      BAR();
    }
  }
}

extern "C" void kernel_launch(void* const* d_in, const int* in_sizes, int n_in,
                              void* d_out, int out_size, void* d_ws, size_t ws_size,
                              hipStream_t stream) {
  const float* x   = (const float*)d_in[0];
  const float* wxr = (const float*)d_in[1];
  const float* wxi = (const float*)d_in[2];
  const float* wxj = (const float*)d_in[3];
  const float* wxk = (const float*)d_in[4];
  const float* wxb = (const float*)d_in[5];
  const float* uhr = (const float*)d_in[6];
  const float* uhi = (const float*)d_in[7];
  const float* uhj = (const float*)d_in[8];
  const float* uhk = (const float*)d_in[9];
  const float* fcw = (const float*)d_in[10];
  const float* fcb = (const float*)d_in[11];
  float* out = (float*)d_out;

  zero_inter<<<dim3(T_ * B_ / 256), dim3(256), 0, stream>>>();
  qlstm_fused<<<dim3(64), dim3(320), 0, stream>>>(
      x, uhr, uhi, uhj, uhk, wxr, wxi, wxj, wxk, wxb, fcw, fcb, out);
}